// Round 11
// baseline (1355.631 us; speedup 1.0000x reference)
//
#include <hip/hip_runtime.h>

// GCN encoder, f32: 2x GCNConv (64 -> 128 -> 64).
// layer1 (aggregate-first): h1 = relu((A_hat @ emb) @ W1 + b1)
// layer2 (transform-first): out = A_hat @ (h1 @ W2) + b2
// Aggregation: dimension-SLICED scatter-gather. 8 slices x 8 dims; block
// (bucket,slice) with slice = blockIdx&7 -> all blocks on one XCD share a
// 1.6 MB slice table (L2-resident) -> random row reads become L2 hits.
// Table is prescaled Y[u] = bf16(dinv[u]*X[u]) so edges carry no weights:
// out[v] = dv*(Y[v] + sum Y[u]) + bias. LDS f32 accumulation per bucket.
// Edge recs (dst_local<<23|src) built by block-local counting sort; the
// per-node CSR permutation (binsort) is eliminated entirely.

constexpr int D_EMB = 64;
constexpr int D_HID = 128;
constexpr int CB_LOG = 9;          // 512 nodes per bucket
constexpr int CB = 1 << CB_LOG;    // requires N <= 2^23, nbuckc <= 256
constexpr int CAP = 16384;         // per-bucket slack (mean E/nbuckc ~ 8163)
constexpr int FB_EPT = 16;
constexpr int FB_CHUNK = 256 * FB_EPT;
constexpr int NSLICE = 8;          // dims sliced across XCDs
constexpr int DPS = 8;             // dims per slice (NSLICE*DPS = 64)

__device__ inline unsigned f2bf1(float f) {  // RNE f32->bf16 (low 16 bits)
    unsigned u = __float_as_uint(f);
    return (u + 0x7FFFu + ((u >> 16) & 1u)) >> 16;
}
__device__ inline float blo(unsigned u) { return __uint_as_float(u << 16); }
__device__ inline float bhi(unsigned u) { return __uint_as_float(u & 0xFFFF0000u); }

// Seed per-bucket append cursors to CAP-strided region starts.
__global__ __launch_bounds__(256) void k_binit(int* __restrict__ bcur) {
    bcur[threadIdx.x * 16] = threadIdx.x * CAP;
}

// Block-local counting sort into coarse buckets (line-coalesced run writes).
__global__ __launch_bounds__(256) void k_fillb(const int* __restrict__ ei,
                                               int* __restrict__ bcur,
                                               unsigned int* __restrict__ recs, int E) {
    __shared__ int hist[4][256];
    __shared__ int lcur[256];
    const int tid  = threadIdx.x;
    const int w    = tid >> 6;
    const int base = blockIdx.x * FB_CHUNK;

    for (int i = tid; i < 4 * 256; i += 256) ((int*)hist)[i] = 0;
    __syncthreads();

    int s[FB_EPT], d[FB_EPT];
#pragma unroll
    for (int i = 0; i < FB_EPT; ++i) {
        int e = base + tid + i * 256;
        if (e < E) {
            s[i] = ei[e];
            d[i] = ei[E + e];
            atomicAdd(&hist[w][d[i] >> CB_LOG], 1);
        } else {
            d[i] = -1;
        }
    }
    __syncthreads();

    int h = hist[0][tid] + hist[1][tid] + hist[2][tid] + hist[3][tid];
    if (h > 0) lcur[tid] = atomicAdd(&bcur[tid * 16], h);
    __syncthreads();

#pragma unroll
    for (int i = 0; i < FB_EPT; ++i) {
        if (d[i] >= 0) {
            int b   = d[i] >> CB_LOG;
            int pos = atomicAdd(&lcur[b], 1);
            recs[pos] = ((unsigned int)(d[i] & (CB - 1)) << 23) | (unsigned int)s[i];
        }
    }
}

// Per-bucket degree histogram -> dinv (rsqrt(deg+1)). No scan, no permute.
__global__ __launch_bounds__(1024) void k_degdinv(const unsigned int* __restrict__ recs,
                                                  const int* __restrict__ bcur,
                                                  float* __restrict__ dinv, int N) {
    __shared__ int h[CB];
    const int b   = blockIdx.x;
    const int tid = threadIdx.x;
    const int n0  = b * CB;
    const int nn  = min(CB, N - n0);
    const int sz  = bcur[b * 16] - b * CAP;
    const unsigned int* rb = recs + (size_t)b * CAP;
    if (tid < nn) h[tid] = 0;
    __syncthreads();
    for (int i = tid; i < sz; i += 1024) atomicAdd(&h[rb[i] >> 23], 1);
    __syncthreads();
    if (tid < nn) dinv[n0 + tid] = rsqrtf((float)(h[tid] + 1));  // +1 self-loop
}

// Y = bf16(dinv[node] * X) in SLICED layout: Ys[s][node] = uint4 (8 bf16).
__global__ __launch_bounds__(256) void k_f2bfY(const float* __restrict__ X,
                                               const float* __restrict__ dinv,
                                               uint4* __restrict__ Ys, int N) {
    int i = blockIdx.x * 256 + threadIdx.x;   // over N*8 (node, slice) tasks
    int stride = gridDim.x * 256;
    int total = N * NSLICE;
    for (; i < total; i += stride) {
        int node = i >> 3, s = i & 7;
        float dv = dinv[node];
        const float* src = X + (size_t)node * 64 + s * DPS;
        float4 a = ((const float4*)src)[0];
        float4 b = ((const float4*)src)[1];
        uint4 o;
        o.x = f2bf1(dv * a.x) | (f2bf1(dv * a.y) << 16);
        o.y = f2bf1(dv * a.z) | (f2bf1(dv * a.w) << 16);
        o.z = f2bf1(dv * b.x) | (f2bf1(dv * b.y) << 16);
        o.w = f2bf1(dv * b.z) | (f2bf1(dv * b.w) << 16);
        Ys[(size_t)s * N + node] = o;
    }
}

// Sliced aggregate: block = (bucket, slice); slice = blockIdx&7 pins each
// slice's 1.6MB table to one XCD's L2. LDS f32 acc, ds_add per edge.
// OUT[v][s*8..] = dv*(Y[v] + sum_{u->v} Y[u]) (+ bias).
template <bool BIAS>
__global__ __launch_bounds__(256) void k_sgather(
    const unsigned int* __restrict__ recs, const int* __restrict__ bcur,
    const uint4* __restrict__ Ys, const float* __restrict__ dinv,
    const float* __restrict__ bias, float* __restrict__ OUT, int N) {
    __shared__ float acc[DPS][CB + 8];   // +8 pad: d shifts banks by 8
    const int bid = blockIdx.x;
    const int s   = bid & (NSLICE - 1);
    const int b   = bid >> 3;
    const int tid = threadIdx.x;
    const int n0  = b * CB;
    const int nn  = min(CB, N - n0);
    const int sz  = bcur[b * 16] - b * CAP;
    const unsigned int* rb = recs + (size_t)b * CAP;
    const uint4* Yt = Ys + (size_t)s * N;

    // init with self-term Y[v] (coalesced)
    for (int i = tid; i < nn; i += 256) {
        uint4 yv = Yt[n0 + i];
        acc[0][i] = blo(yv.x); acc[1][i] = bhi(yv.x);
        acc[2][i] = blo(yv.y); acc[3][i] = bhi(yv.y);
        acc[4][i] = blo(yv.z); acc[5][i] = bhi(yv.z);
        acc[6][i] = blo(yv.w); acc[7][i] = bhi(yv.w);
    }
    __syncthreads();

#define ACC8(dl, yv)                                                       \
    atomicAdd(&acc[0][dl], blo((yv).x)); atomicAdd(&acc[1][dl], bhi((yv).x)); \
    atomicAdd(&acc[2][dl], blo((yv).y)); atomicAdd(&acc[3][dl], bhi((yv).y)); \
    atomicAdd(&acc[4][dl], blo((yv).z)); atomicAdd(&acc[5][dl], bhi((yv).z)); \
    atomicAdd(&acc[6][dl], blo((yv).w)); atomicAdd(&acc[7][dl], bhi((yv).w));

    // edges: 4 in flight per thread (L2-latency hiding)
    int i = tid;
    for (; i + 768 < sz; i += 1024) {
        unsigned r0 = rb[i], r1 = rb[i + 256], r2 = rb[i + 512], r3 = rb[i + 768];
        uint4 y0 = Yt[r0 & 0x7FFFFF];
        uint4 y1 = Yt[r1 & 0x7FFFFF];
        uint4 y2 = Yt[r2 & 0x7FFFFF];
        uint4 y3 = Yt[r3 & 0x7FFFFF];
        int d0 = r0 >> 23, d1 = r1 >> 23, d2 = r2 >> 23, d3 = r3 >> 23;
        ACC8(d0, y0); ACC8(d1, y1); ACC8(d2, y2); ACC8(d3, y3);
    }
    for (; i < sz; i += 256) {
        unsigned r = rb[i];
        uint4 yv = Yt[r & 0x7FFFFF];
        int d = r >> 23;
        ACC8(d, yv);
    }
#undef ACC8
    __syncthreads();

    float bb[DPS];
#pragma unroll
    for (int d = 0; d < DPS; ++d) bb[d] = BIAS ? bias[s * DPS + d] : 0.f;

    for (int i2 = tid; i2 < nn; i2 += 256) {
        float dv = dinv[n0 + i2];
        float* orow = OUT + (size_t)(n0 + i2) * 64 + s * DPS;
        ((float4*)orow)[0] = make_float4(
            fmaf(dv, acc[0][i2], bb[0]), fmaf(dv, acc[1][i2], bb[1]),
            fmaf(dv, acc[2][i2], bb[2]), fmaf(dv, acc[3][i2], bb[3]));
        ((float4*)orow)[1] = make_float4(
            fmaf(dv, acc[4][i2], bb[4]), fmaf(dv, acc[5][i2], bb[5]),
            fmaf(dv, acc[6][i2], bb[6]), fmaf(dv, acc[7][i2], bb[7]));
    }
}

// X = A @ W. Epilogue: optional bias/ReLU; output f32 row-major, or
// (OUTBF) prescaled-by-dinv bf16 in the SLICED layout for k_sgather.
template <int K, int OUT, int BM, bool BIAS, bool RELU, bool OUTBF>
__global__ __launch_bounds__(256) void k_gemm(
    const float* __restrict__ A, const float* __restrict__ W,
    const float* __restrict__ bias, const float* __restrict__ dinv,
    void* __restrict__ Xout, int N) {
    constexpr int NCG = OUT / 4;
    constexpr int NRG = 256 / NCG;
    constexpr int RPT = BM / NRG;

    __shared__ float As[BM][K + 1];
    __shared__ float Ws[K][OUT];

    const int tid  = threadIdx.x;
    const int row0 = blockIdx.x * BM;

    for (int i = tid; i < K * OUT / 4; i += 256)
        ((float4*)Ws)[i] = ((const float4*)W)[i];

    for (int i = tid; i < BM * K / 4; i += 256) {
        int r  = i / (K / 4);
        int k4 = i % (K / 4);
        int row = row0 + r;
        float4 v = make_float4(0.f, 0.f, 0.f, 0.f);
        if (row < N) v = ((const float4*)(A + (size_t)row * K))[k4];
        As[r][k4 * 4 + 0] = v.x;
        As[r][k4 * 4 + 1] = v.y;
        As[r][k4 * 4 + 2] = v.z;
        As[r][k4 * 4 + 3] = v.w;
    }
    __syncthreads();

    const int tc = tid % NCG;
    const int tr = tid / NCG;
    const int r0 = tr * RPT;

    float acc[RPT][4];
#pragma unroll
    for (int i = 0; i < RPT; ++i)
        acc[i][0] = acc[i][1] = acc[i][2] = acc[i][3] = 0.f;

#pragma unroll 8
    for (int k = 0; k < K; ++k) {
        float4 w = *(const float4*)&Ws[k][tc * 4];
#pragma unroll
        for (int i = 0; i < RPT; ++i) {
            float a = As[r0 + i][k];
            acc[i][0] = fmaf(a, w.x, acc[i][0]);
            acc[i][1] = fmaf(a, w.y, acc[i][1]);
            acc[i][2] = fmaf(a, w.z, acc[i][2]);
            acc[i][3] = fmaf(a, w.w, acc[i][3]);
        }
    }

    float4 bb = make_float4(0.f, 0.f, 0.f, 0.f);
    if (BIAS) bb = ((const float4*)bias)[tc];

#pragma unroll
    for (int i = 0; i < RPT; ++i) {
        int row = row0 + r0 + i;
        if (row >= N) break;
        float4 v = make_float4(acc[i][0], acc[i][1], acc[i][2], acc[i][3]);
        if (BIAS) { v.x += bb.x; v.y += bb.y; v.z += bb.z; v.w += bb.w; }
        if (RELU) {
            v.x = fmaxf(v.x, 0.f); v.y = fmaxf(v.y, 0.f);
            v.z = fmaxf(v.z, 0.f); v.w = fmaxf(v.w, 0.f);
        }
        if (OUTBF) {
            // sliced bf16 write, prescaled by dinv[row]; tc covers half a slice
            float dvr = dinv[row];
            v.x *= dvr; v.y *= dvr; v.z *= dvr; v.w *= dvr;
            uint2 p;
            p.x = f2bf1(v.x) | (f2bf1(v.y) << 16);
            p.y = f2bf1(v.z) | (f2bf1(v.w) << 16);
            int sl = tc >> 1, half = tc & 1;
            unsigned* Xb = (unsigned*)Xout;
            *(uint2*)(Xb + ((size_t)sl * N + row) * 4 + half * 2) = p;
        } else {
            ((float4*)((float*)Xout + (size_t)row * OUT))[tc] = v;
        }
    }
}

extern "C" void kernel_launch(void* const* d_in, const int* in_sizes, int n_in,
                              void* d_out, int out_size, void* d_ws, size_t ws_size,
                              hipStream_t stream) {
    const float* emb = (const float*)d_in[0];
    const float* W1  = (const float*)d_in[1];
    const float* b1  = (const float*)d_in[2];
    const float* W2  = (const float*)d_in[3];
    const float* b2  = (const float*)d_in[4];
    const int*   ei  = (const int*)d_in[5];

    const int N = in_sizes[0] / D_EMB;
    const int E = in_sizes[5] / 2;
    const int nbuckc = (N + CB - 1) / CB;   // 196 for N=100k (<=256)

    // Workspace: a1[N*64 f32] | h1[N*128 f32] | Yb[8*N uint4] | recs[nbuckc*CAP]
    //            | bcur[256*16] | dinv[N]
    float*        a1   = (float*)d_ws;
    float*        h1   = a1 + (size_t)N * D_EMB;
    uint4*        Yb   = (uint4*)(h1 + (size_t)N * D_HID);
    unsigned int* recs = (unsigned int*)(Yb + (size_t)NSLICE * N);
    int*          bcur = (int*)(recs + (size_t)nbuckc * CAP);
    float*        dinv = (float*)(bcur + 256 * 16);
    float*        out  = (float*)d_out;

    const int nbFb = (E + FB_CHUNK - 1) / FB_CHUNK;   // 391

    // Edge bucketing + degrees (no CSR permutation needed)
    k_binit<<<1, 256, 0, stream>>>(bcur);
    k_fillb<<<nbFb, 256, 0, stream>>>(ei, bcur, recs, E);
    k_degdinv<<<nbuckc, 1024, 0, stream>>>(recs, bcur, dinv, N);

    // Layer 1: Y1 = bf16(dinv*emb); a1 = dv*(Y1[v]+sum Y1[u]); h1 = relu(a1@W1+b1)
    k_f2bfY<<<2048, 256, 0, stream>>>(emb, dinv, Yb, N);
    k_sgather<false><<<nbuckc * NSLICE, 256, 0, stream>>>(recs, bcur, Yb, dinv, nullptr, a1, N);
    k_gemm<D_EMB, D_HID, 64, true, true, false><<<(N + 63) / 64, 256, 0, stream>>>(
        a1, W1, b1, nullptr, h1, N);

    // Layer 2: Y2 = bf16(dinv*(h1@W2)) sliced; out = dv*(Y2[v]+sum Y2[u]) + b2
    k_gemm<D_HID, D_EMB, 32, false, false, true><<<(N + 31) / 32, 256, 0, stream>>>(
        h1, W2, nullptr, dinv, Yb, N);
    k_sgather<true><<<nbuckc * NSLICE, 256, 0, stream>>>(recs, bcur, Yb, dinv, b2, out, N);
}

// Round 12
// 381.374 us; speedup vs baseline: 3.5546x; 3.5546x over previous
//
#include <hip/hip_runtime.h>

// GCN encoder, f32: 2x GCNConv (64 -> 128 -> 64).
// layer1 (aggregate-first): h1 = relu((A_hat @ emb) @ W1 + b1)
// layer2 (transform-first): out = A_hat @ (h1 @ W2) + b2
// Aggregation: dimension-sliced REGISTER gather. 8 slices x 8 dims; block
// (node-group, slice) with slice = blockIdx&7 -> each XCD's blocks share a
// 1.6 MB slice table (L2-resident). Tables prescaled Y[u]=bf16(dinv[u]*X[u]).
// Per node: 16-lane quarter, one lane per edge, register acc + shfl reduce.
// NO LDS atomics (R11 lesson: LDS float atomicAdd is catastrophically slow).
// CSR-by-dst via block-local counting sort (R9-proven).

constexpr int D_EMB = 64;
constexpr int D_HID = 128;
constexpr int CB_LOG = 9;          // 512 nodes per bucket
constexpr int CB = 1 << CB_LOG;    // requires N <= 2^23, nbuckc <= 256
constexpr int CAP = 16384;         // per-bucket slack (mean E/nbuckc ~ 8163)
constexpr int FB_EPT = 16;
constexpr int FB_CHUNK = 256 * FB_EPT;
constexpr int NSLICE = 8;          // dims sliced across XCDs
constexpr int DPS = 8;             // dims per slice

__device__ inline unsigned f2bf1(float f) {  // RNE f32->bf16 (low 16 bits)
    unsigned u = __float_as_uint(f);
    return (u + 0x7FFFu + ((u >> 16) & 1u)) >> 16;
}
__device__ inline float blo(unsigned u) { return __uint_as_float(u << 16); }
__device__ inline float bhi(unsigned u) { return __uint_as_float(u & 0xFFFF0000u); }

// Seed per-bucket append cursors to CAP-strided region starts.
__global__ __launch_bounds__(256) void k_binit(int* __restrict__ bcur) {
    bcur[threadIdx.x * 16] = threadIdx.x * CAP;
}

// Block-local counting sort into coarse buckets (line-coalesced run writes).
__global__ __launch_bounds__(256) void k_fillb(const int* __restrict__ ei,
                                               int* __restrict__ bcur,
                                               unsigned int* __restrict__ recs, int E) {
    __shared__ int hist[4][256];
    __shared__ int lcur[256];
    const int tid  = threadIdx.x;
    const int w    = tid >> 6;
    const int base = blockIdx.x * FB_CHUNK;

    for (int i = tid; i < 4 * 256; i += 256) ((int*)hist)[i] = 0;
    __syncthreads();

    int s[FB_EPT], d[FB_EPT];
#pragma unroll
    for (int i = 0; i < FB_EPT; ++i) {
        int e = base + tid + i * 256;
        if (e < E) {
            s[i] = ei[e];
            d[i] = ei[E + e];
            atomicAdd(&hist[w][d[i] >> CB_LOG], 1);
        } else {
            d[i] = -1;
        }
    }
    __syncthreads();

    int h = hist[0][tid] + hist[1][tid] + hist[2][tid] + hist[3][tid];
    if (h > 0) lcur[tid] = atomicAdd(&bcur[tid * 16], h);
    __syncthreads();

#pragma unroll
    for (int i = 0; i < FB_EPT; ++i) {
        if (d[i] >= 0) {
            int b   = d[i] >> CB_LOG;
            int pos = atomicAdd(&lcur[b], 1);
            recs[pos] = ((unsigned int)(d[i] & (CB - 1)) << 23) | (unsigned int)s[i];
        }
    }
}

// Bucket sizes from cursors -> exclusive scan -> bbase. row_ptr[N] = E.
__global__ __launch_bounds__(256) void k_bscan(const int* __restrict__ bcur,
                                               int* __restrict__ bbase,
                                               int* __restrict__ row_ptr,
                                               int nbuckc, int N, int E) {
    __shared__ int ts[256];
    const int tid = threadIdx.x;
    int s = (tid < nbuckc) ? (bcur[tid * 16] - tid * CAP) : 0;
    ts[tid] = s;
    __syncthreads();
    for (int off = 1; off < 256; off <<= 1) {
        int t = (tid >= off) ? ts[tid - off] : 0;
        __syncthreads();
        ts[tid] += t;
        __syncthreads();
    }
    if (tid < nbuckc) bbase[tid] = ts[tid] - s;
    if (tid == nbuckc - 1) bbase[nbuckc] = ts[tid];  // = E
    if (tid == 0) row_ptr[N] = E;
}

// Per coarse bucket: LDS degree histogram -> LDS scan -> row_ptr + dinv,
// then bin records to srcs[]. (int LDS atomics here are fine: histogram-
// scale, not per-edge-per-dim.)
__global__ __launch_bounds__(1024) void k_binsort(const unsigned int* __restrict__ recs,
                                                  const int* __restrict__ bbase,
                                                  int* __restrict__ row_ptr,
                                                  float* __restrict__ dinv,
                                                  unsigned int* __restrict__ srcs, int N) {
    __shared__ int ld[CB];
    const int b   = blockIdx.x;
    const int n0  = b * CB;
    const int tid = threadIdx.x;
    const int nn  = min(CB, N - n0);
    const int obeg = bbase[b];
    const int sz   = bbase[b + 1] - obeg;
    const unsigned int* rb = recs + (size_t)b * CAP;

    if (tid < nn) ld[tid] = 0;
    __syncthreads();

    for (int i = tid; i < sz; i += 1024)
        atomicAdd(&ld[rb[i] >> 23], 1);
    __syncthreads();

    int own = (tid < nn) ? ld[tid] : 0;
    for (int off = 1; off < CB; off <<= 1) {
        int t = (tid >= off && tid < nn) ? ld[tid - off] : 0;
        __syncthreads();
        if (tid < nn) ld[tid] += t;
        __syncthreads();
    }
    int incl = (tid < nn) ? ld[tid] : 0;
    __syncthreads();
    if (tid < nn) {
        int rp = obeg + incl - own;
        row_ptr[n0 + tid] = rp;
        dinv[n0 + tid] = rsqrtf((float)(own + 1));   // +1 self-loop
        ld[tid] = rp;
    }
    __syncthreads();

    for (int i = tid; i < sz; i += 1024) {
        unsigned int rec = rb[i];
        int pos = atomicAdd(&ld[rec >> 23], 1);
        srcs[pos] = rec & 0x7FFFFF;
    }
}

// Y = bf16(dinv[node] * X) in SLICED layout: Ys[s][node] = uint4 (8 bf16).
__global__ __launch_bounds__(256) void k_f2bfY(const float* __restrict__ X,
                                               const float* __restrict__ dinv,
                                               uint4* __restrict__ Ys, int N) {
    int i = blockIdx.x * 256 + threadIdx.x;   // over N*8 (node, slice) tasks
    int stride = gridDim.x * 256;
    int total = N * NSLICE;
    for (; i < total; i += stride) {
        int node = i >> 3, s = i & 7;
        float dv = dinv[node];
        const float* src = X + (size_t)node * 64 + s * DPS;
        float4 a = ((const float4*)src)[0];
        float4 b = ((const float4*)src)[1];
        uint4 o;
        o.x = f2bf1(dv * a.x) | (f2bf1(dv * a.y) << 16);
        o.y = f2bf1(dv * a.z) | (f2bf1(dv * a.w) << 16);
        o.z = f2bf1(dv * b.x) | (f2bf1(dv * b.y) << 16);
        o.w = f2bf1(dv * b.z) | (f2bf1(dv * b.w) << 16);
        Ys[(size_t)s * N + node] = o;
    }
}

// Sliced register gather: block = (16-node group, slice = blockIdx&7).
// Quarter (16 lanes) per node; lane per edge; 8 f32 acc in registers;
// 4-step shfl_xor reduce; lanes 0/1 write the two float4 halves.
// OUT[v][s*8..] = dv*(Y[v] + sum_{u->v} Y[u]) (+ bias).
template <bool BIAS>
__global__ __launch_bounds__(256) void k_sgat(
    const int* __restrict__ row_ptr, const unsigned int* __restrict__ srcs,
    const uint4* __restrict__ Ys, const float* __restrict__ dinv,
    const float* __restrict__ bias, float* __restrict__ OUT, int N) {
    const int tid  = threadIdx.x;
    const int l    = tid & 15;              // lane within quarter
    const int q    = tid >> 4;              // quarter 0..15
    const int s    = blockIdx.x & (NSLICE - 1);
    const int node = (blockIdx.x >> 3) * 16 + q;
    if (node >= N) return;
    const uint4* Yt = Ys + (size_t)s * N;
    const int beg = row_ptr[node];
    const int end = row_ptr[node + 1];

    float a0 = 0.f, a1 = 0.f, a2 = 0.f, a3 = 0.f;
    float a4 = 0.f, a5 = 0.f, a6 = 0.f, a7 = 0.f;

    for (int j = beg + l; j < end; j += 16) {
        uint4 y = Yt[srcs[j]];
        a0 += blo(y.x); a1 += bhi(y.x);
        a2 += blo(y.y); a3 += bhi(y.y);
        a4 += blo(y.z); a5 += bhi(y.z);
        a6 += blo(y.w); a7 += bhi(y.w);
    }

#pragma unroll
    for (int m = 1; m <= 8; m <<= 1) {
        a0 += __shfl_xor(a0, m); a1 += __shfl_xor(a1, m);
        a2 += __shfl_xor(a2, m); a3 += __shfl_xor(a3, m);
        a4 += __shfl_xor(a4, m); a5 += __shfl_xor(a5, m);
        a6 += __shfl_xor(a6, m); a7 += __shfl_xor(a7, m);
    }

    if (l < 2) {
        const float dv = dinv[node];
        uint4 y = Yt[node];                 // self term (prescaled)
        float* orow = OUT + (size_t)node * 64 + s * DPS;
        if (l == 0) {
            a0 += blo(y.x); a1 += bhi(y.x);
            a2 += blo(y.y); a3 += bhi(y.y);
            float4 r = make_float4(dv * a0, dv * a1, dv * a2, dv * a3);
            if (BIAS) {
                r.x += bias[s * DPS + 0]; r.y += bias[s * DPS + 1];
                r.z += bias[s * DPS + 2]; r.w += bias[s * DPS + 3];
            }
            ((float4*)orow)[0] = r;
        } else {
            a4 += blo(y.z); a5 += bhi(y.z);
            a6 += blo(y.w); a7 += bhi(y.w);
            float4 r = make_float4(dv * a4, dv * a5, dv * a6, dv * a7);
            if (BIAS) {
                r.x += bias[s * DPS + 4]; r.y += bias[s * DPS + 5];
                r.z += bias[s * DPS + 6]; r.w += bias[s * DPS + 7];
            }
            ((float4*)orow)[1] = r;
        }
    }
}

// X = A @ W. Epilogue: optional bias/ReLU; output f32 row-major, or
// (OUTBF) prescaled-by-dinv bf16 in the SLICED layout for k_sgat.
template <int K, int OUT, int BM, bool BIAS, bool RELU, bool OUTBF>
__global__ __launch_bounds__(256) void k_gemm(
    const float* __restrict__ A, const float* __restrict__ W,
    const float* __restrict__ bias, const float* __restrict__ dinv,
    void* __restrict__ Xout, int N) {
    constexpr int NCG = OUT / 4;
    constexpr int NRG = 256 / NCG;
    constexpr int RPT = BM / NRG;

    __shared__ float As[BM][K + 1];
    __shared__ float Ws[K][OUT];

    const int tid  = threadIdx.x;
    const int row0 = blockIdx.x * BM;

    for (int i = tid; i < K * OUT / 4; i += 256)
        ((float4*)Ws)[i] = ((const float4*)W)[i];

    for (int i = tid; i < BM * K / 4; i += 256) {
        int r  = i / (K / 4);
        int k4 = i % (K / 4);
        int row = row0 + r;
        float4 v = make_float4(0.f, 0.f, 0.f, 0.f);
        if (row < N) v = ((const float4*)(A + (size_t)row * K))[k4];
        As[r][k4 * 4 + 0] = v.x;
        As[r][k4 * 4 + 1] = v.y;
        As[r][k4 * 4 + 2] = v.z;
        As[r][k4 * 4 + 3] = v.w;
    }
    __syncthreads();

    const int tc = tid % NCG;
    const int tr = tid / NCG;
    const int r0 = tr * RPT;

    float acc[RPT][4];
#pragma unroll
    for (int i = 0; i < RPT; ++i)
        acc[i][0] = acc[i][1] = acc[i][2] = acc[i][3] = 0.f;

#pragma unroll 8
    for (int k = 0; k < K; ++k) {
        float4 w = *(const float4*)&Ws[k][tc * 4];
#pragma unroll
        for (int i = 0; i < RPT; ++i) {
            float a = As[r0 + i][k];
            acc[i][0] = fmaf(a, w.x, acc[i][0]);
            acc[i][1] = fmaf(a, w.y, acc[i][1]);
            acc[i][2] = fmaf(a, w.z, acc[i][2]);
            acc[i][3] = fmaf(a, w.w, acc[i][3]);
        }
    }

    float4 bb = make_float4(0.f, 0.f, 0.f, 0.f);
    if (BIAS) bb = ((const float4*)bias)[tc];

#pragma unroll
    for (int i = 0; i < RPT; ++i) {
        int row = row0 + r0 + i;
        if (row >= N) break;
        float4 v = make_float4(acc[i][0], acc[i][1], acc[i][2], acc[i][3]);
        if (BIAS) { v.x += bb.x; v.y += bb.y; v.z += bb.z; v.w += bb.w; }
        if (RELU) {
            v.x = fmaxf(v.x, 0.f); v.y = fmaxf(v.y, 0.f);
            v.z = fmaxf(v.z, 0.f); v.w = fmaxf(v.w, 0.f);
        }
        if (OUTBF) {
            // sliced bf16 write, prescaled by dinv[row]; tc covers half a slice
            float dvr = dinv[row];
            v.x *= dvr; v.y *= dvr; v.z *= dvr; v.w *= dvr;
            uint2 p;
            p.x = f2bf1(v.x) | (f2bf1(v.y) << 16);
            p.y = f2bf1(v.z) | (f2bf1(v.w) << 16);
            int sl = tc >> 1, half = tc & 1;
            unsigned* Xb = (unsigned*)Xout;
            *(uint2*)(Xb + ((size_t)sl * N + row) * 4 + half * 2) = p;
        } else {
            ((float4*)((float*)Xout + (size_t)row * OUT))[tc] = v;
        }
    }
}

extern "C" void kernel_launch(void* const* d_in, const int* in_sizes, int n_in,
                              void* d_out, int out_size, void* d_ws, size_t ws_size,
                              hipStream_t stream) {
    const float* emb = (const float*)d_in[0];
    const float* W1  = (const float*)d_in[1];
    const float* b1  = (const float*)d_in[2];
    const float* W2  = (const float*)d_in[3];
    const float* b2  = (const float*)d_in[4];
    const int*   ei  = (const int*)d_in[5];

    const int N = in_sizes[0] / D_EMB;
    const int E = in_sizes[5] / 2;
    const int nbuckc = (N + CB - 1) / CB;   // 196 for N=100k (<=256)

    // Workspace: a1[N*64 f32] | h1[N*128 f32] | Yb[8*N uint4] | srcs[E]
    //            | recs[nbuckc*CAP] | row_ptr[N+1] | bcur[256*16] | bbase[257] | dinv[N]
    float*        a1      = (float*)d_ws;
    float*        h1      = a1 + (size_t)N * D_EMB;
    uint4*        Yb      = (uint4*)(h1 + (size_t)N * D_HID);
    unsigned int* srcs    = (unsigned int*)(Yb + (size_t)NSLICE * N);
    unsigned int* recs    = srcs + E;
    int*          row_ptr = (int*)(recs + (size_t)nbuckc * CAP);
    int*          bcur    = row_ptr + (N + 1);
    int*          bbase   = bcur + 256 * 16;
    float*        dinv    = (float*)(bbase + 257);
    float*        out     = (float*)d_out;

    const int nbFb  = (E + FB_CHUNK - 1) / FB_CHUNK;        // 391
    const int nbSg  = ((N + 15) / 16) * NSLICE;             // 50000

    // CSR-by-dst build
    k_binit<<<1, 256, 0, stream>>>(bcur);
    k_fillb<<<nbFb, 256, 0, stream>>>(ei, bcur, recs, E);
    k_bscan<<<1, 256, 0, stream>>>(bcur, bbase, row_ptr, nbuckc, N, E);
    k_binsort<<<nbuckc, 1024, 0, stream>>>(recs, bbase, row_ptr, dinv, srcs, N);

    // Layer 1: Y1 = bf16(dinv*emb) sliced; a1 = dv*(Y1[v]+sum Y1[u]); h1 = relu(a1@W1+b1)
    k_f2bfY<<<2048, 256, 0, stream>>>(emb, dinv, Yb, N);
    k_sgat<false><<<nbSg, 256, 0, stream>>>(row_ptr, srcs, Yb, dinv, nullptr, a1, N);
    k_gemm<D_EMB, D_HID, 64, true, true, false><<<(N + 63) / 64, 256, 0, stream>>>(
        a1, W1, b1, nullptr, h1, N);

    // Layer 2: Y2 = bf16(dinv*(h1@W2)) sliced; out = dv*(Y2[v]+sum Y2[u]) + b2
    k_gemm<D_HID, D_EMB, 32, false, false, true><<<(N + 31) / 32, 256, 0, stream>>>(
        h1, W2, nullptr, dinv, Yb, N);
    k_sgat<true><<<nbSg, 256, 0, stream>>>(row_ptr, srcs, Yb, dinv, b2, out, N);
}